// Round 2
// baseline (351.745 us; speedup 1.0000x reference)
//
#include <hip/hip_runtime.h>
#include <hip/hip_fp16.h>

#define FDIM 128
#define HEADS 4
#define CD 32
#define BM 64
#define NB 8            // XCD buckets

typedef __attribute__((ext_vector_type(8))) short bfrag;   // 8 bf16 (4 VGPRs)
typedef __attribute__((ext_vector_type(4))) float ffrag;   // 4 f32 accum

static __device__ __forceinline__ unsigned short f2bf(float v) {
    unsigned u = __float_as_uint(v);
    u += 0x7FFF + ((u >> 16) & 1);          // round-nearest-even
    return (unsigned short)(u >> 16);
}
static __device__ __forceinline__ float bf2f(unsigned short u) {
    return __uint_as_float(((unsigned)u) << 16);
}

// meta layout (ints): [0..7] bucket counts, [8..16] base (exclusive scan, base[8]=E),
//                     [17..24] cursors for esum reservations
// K0: split W into bf16 hi/lo, transpose to [n][k]; also zero meta.
__global__ __launch_bounds__(256) void k_wsplit(const float* __restrict__ w,
                                                unsigned short* __restrict__ wt_hi,
                                                unsigned short* __restrict__ wt_lo,
                                                int* __restrict__ meta)
{
    int i = blockIdx.x * 256 + threadIdx.x;      // 16384 elements, coalesced read
    if (i < 32) meta[i] = 0;
    float v = w[i];
    unsigned short h = f2bf(v);
    float r = v - bf2f(h);
    int k = i >> 7, n = i & 127;
    wt_hi[n * FDIM + k] = h;
    wt_lo[n * FDIM + k] = f2bf(r);
}

// K0b: bucket histogram over source nodes (LDS-aggregated, 512 blocks grid-stride).
__global__ __launch_bounds__(256) void k_hist(const int* __restrict__ ei, int E, int N,
                                              int* __restrict__ meta)
{
    __shared__ int h[NB];
    int t = threadIdx.x;
    if (t < NB) h[t] = 0;
    __syncthreads();
    for (int e = blockIdx.x * 256 + t; e < E; e += gridDim.x * 256)
        atomicAdd(&h[(ei[e] * NB) / N], 1);
    __syncthreads();
    if (t < NB) atomicAdd(&meta[t], h[t]);
}

// K0c: 8-element exclusive scan -> base + init cursors.
__global__ void k_scan8(int* __restrict__ meta)
{
    if (threadIdx.x == 0) {
        int s = 0;
        for (int b = 0; b < NB; b++) { int c = meta[b]; meta[8 + b] = s; meta[17 + b] = s; s += c; }
        meta[16] = s;
    }
}

// K1: MFMA GEMM (split bf16: hi*hi + hi*lo + lo*hi ~= fp32) + logits. Unchanged.
__global__ __launch_bounds__(256) void k_gemm(const float* __restrict__ x,
                                              const unsigned short* __restrict__ wt_hi,
                                              const unsigned short* __restrict__ wt_lo,
                                              const float* __restrict__ att,
                                              unsigned short* __restrict__ xwh,
                                              float* __restrict__ a_src,
                                              float* __restrict__ a_dst,
                                              float4* __restrict__ zero_base,
                                              int nz4, int N)
{
    __shared__ float accs[BM * 132];     // 64 rows x 128 cols, stride 132 (33.8KB)
    __shared__ float attl[HEADS * 2 * CD];
    int t = threadIdx.x;
    int row0 = blockIdx.x * BM;
    for (int i = blockIdx.x * 256 + t; i < nz4; i += gridDim.x * 256)
        zero_base[i] = make_float4(0.f, 0.f, 0.f, 0.f);
    attl[t] = att[t];

    int l = t & 63, wv = t >> 6;
    int la = l & 15, lr = l >> 4;
    int arow = row0 + wv * 16 + la;
    bool aval = arow < N;
    const float* xbase = x + (size_t)arow * FDIM + lr * 8;

    ffrag acc[8] = {};
#pragma unroll
    for (int ks = 0; ks < 4; ks++) {
        float xv[8] = {0.f, 0.f, 0.f, 0.f, 0.f, 0.f, 0.f, 0.f};
        if (aval) {
            float4 f0 = *(const float4*)(xbase + ks * 32);
            float4 f1 = *(const float4*)(xbase + ks * 32 + 4);
            xv[0] = f0.x; xv[1] = f0.y; xv[2] = f0.z; xv[3] = f0.w;
            xv[4] = f1.x; xv[5] = f1.y; xv[6] = f1.z; xv[7] = f1.w;
        }
        bfrag ah, al;
#pragma unroll
        for (int j = 0; j < 8; j++) {
            unsigned short h = f2bf(xv[j]);
            ah[j] = (short)h;
            al[j] = (short)f2bf(xv[j] - bf2f(h));
        }
        int boff = ks * 32 + lr * 8;
#pragma unroll
        for (int ct = 0; ct < 8; ct++) {
            int o = (ct * 16 + la) * FDIM + boff;
            bfrag bh = *(const bfrag*)(wt_hi + o);
            bfrag bl = *(const bfrag*)(wt_lo + o);
            acc[ct] = __builtin_amdgcn_mfma_f32_16x16x32_bf16(ah, bh, acc[ct], 0, 0, 0);
            acc[ct] = __builtin_amdgcn_mfma_f32_16x16x32_bf16(ah, bl, acc[ct], 0, 0, 0);
            acc[ct] = __builtin_amdgcn_mfma_f32_16x16x32_bf16(al, bh, acc[ct], 0, 0, 0);
        }
    }

#pragma unroll
    for (int i = 0; i < 4; i++) {
        int r = row0 + wv * 16 + lr * 4 + i;
        if (r < N) {
            uint2 pa, pb;
            pa.x = (unsigned)f2bf(acc[0][i]) | ((unsigned)f2bf(acc[2][i]) << 16);
            pa.y = (unsigned)f2bf(acc[4][i]) | ((unsigned)f2bf(acc[6][i]) << 16);
            pb.x = (unsigned)f2bf(acc[1][i]) | ((unsigned)f2bf(acc[3][i]) << 16);
            pb.y = (unsigned)f2bf(acc[5][i]) | ((unsigned)f2bf(acc[7][i]) << 16);
            *(uint2*)&xwh[(size_t)r * FDIM + la * 4] = pa;
            *(uint2*)&xwh[(size_t)r * FDIM + 64 + la * 4] = pb;
        }
    }
#pragma unroll
    for (int ct = 0; ct < 8; ct++)
#pragma unroll
        for (int i = 0; i < 4; i++)
            accs[(wv * 16 + lr * 4 + i) * 132 + ct * 16 + la] = acc[ct][i];
    __syncthreads();
    int row = t >> 2, h = t & 3;
    const float* ap = &attl[h * 2 * CD];
    const float* xr = &accs[row * 132 + h * CD];
    float s = 0.f, d = 0.f;
#pragma unroll 8
    for (int c = 0; c < CD; c++) { float v = xr[c]; s += v * ap[c]; d += v * ap[CD + c]; }
    int n = row0 + row;
    if (n < N) { a_src[n * 4 + h] = s; a_dst[n * 4 + h] = d; }
}

// K4: per-edge alpha + seg atomics + bucketed record emit (counting sort by r-range).
// record = (r, cl, half2(ex0,ex1), half2(ex2,ex3)) = 16B.
__global__ __launch_bounds__(256) void k_esum(const int* __restrict__ ei, int E, int N,
                                              const float* __restrict__ a_src,
                                              const float* __restrict__ a_dst,
                                              float* __restrict__ seg,
                                              int* __restrict__ meta,
                                              uint4* __restrict__ recs)
{
    __shared__ int lcnt[NB];
    __shared__ int gbase[NB];
    int t = threadIdx.x;
    if (t < NB) lcnt[t] = 0;
    __syncthreads();
    int e = blockIdx.x * 256 + t;
    bool v = e < E;
    int r = 0, cl = 0, b = 0, loc = 0;
    unsigned a01 = 0, a23 = 0;
    if (v) {
        r = ei[e]; cl = ei[E + e];
        float4 as = *(const float4*)&a_src[r * 4];
        float4 ad = *(const float4*)&a_dst[cl * 4];
        float x0 = as.x + ad.x; x0 = x0 >= 0.f ? x0 : 0.2f * x0;
        float x1 = as.y + ad.y; x1 = x1 >= 0.f ? x1 : 0.2f * x1;
        float x2 = as.z + ad.z; x2 = x2 >= 0.f ? x2 : 0.2f * x2;
        float x3 = as.w + ad.w; x3 = x3 >= 0.f ? x3 : 0.2f * x3;
        float e0 = __expf(x0), e1 = __expf(x1), e2 = __expf(x2), e3 = __expf(x3);
        atomicAdd(&seg[r * 4 + 0], e0);
        atomicAdd(&seg[r * 4 + 1], e1);
        atomicAdd(&seg[r * 4 + 2], e2);
        atomicAdd(&seg[r * 4 + 3], e3);
        __half2 p01 = __floats2half2_rn(e0, e1);
        __half2 p23 = __floats2half2_rn(e2, e3);
        a01 = *(unsigned*)&p01;
        a23 = *(unsigned*)&p23;
        b = (r * NB) / N;
        loc = atomicAdd(&lcnt[b], 1);
    }
    __syncthreads();
    if (t < NB && lcnt[t] > 0) gbase[t] = atomicAdd(&meta[17 + t], lcnt[t]);
    __syncthreads();
    if (v) recs[gbase[b] + loc] = make_uint4((unsigned)r, (unsigned)cl, a01, a23);
}

// K5: bucketed scatter — block bid handles bucket bid%8 (XCD-aligned via round-robin
// dispatch), so the xwh gather working set is 1.6MB -> per-XCD L2-resident.
// 16 lanes/edge as before; grid-stride over chunks for distribution robustness.
__global__ __launch_bounds__(256) void k_scatter(const uint4* __restrict__ recs,
                                                 const int* __restrict__ meta,
                                                 const float* __restrict__ seg,
                                                 const unsigned short* __restrict__ xwh,
                                                 __half2* __restrict__ out_acc2, int bpb)
{
    int t = threadIdx.x;
    int le = t >> 4, c2 = t & 15, lane = t & 63;   // 16 edges/block
    int b = blockIdx.x & 7;
    int lo = meta[8 + b], hi = meta[9 + b];
    int cnt = hi - lo;
    for (int chunk = blockIdx.x >> 3; chunk * 16 < cnt; chunk += bpb) {
        int idx = lo + chunk * 16 + le;
        bool v = idx < hi;
        uint4 rec = recs[v ? idx : lo];
        int r = (int)rec.x, cl = (int)rec.y;
        float av = 0.f;
        if (v && c2 < 4) {
            unsigned az = (c2 < 2) ? rec.z : rec.w;       // no runtime reg indexing
            __half2 hh = *(__half2*)&az;
            float a = (c2 & 1) ? __high2float(hh) : __low2float(hh);
            av = 0.25f * a / (seg[r * 4 + c2] + 1e-16f);
        }
        uint4 q = ((const uint4*)(xwh + (size_t)r * FDIM))[c2];
        float a0 = __shfl(av, (lane & 48) + 0, 64);
        float a1 = __shfl(av, (lane & 48) + 1, 64);
        float a2 = __shfl(av, (lane & 48) + 2, 64);
        float a3 = __shfl(av, (lane & 48) + 3, 64);
        float v0 = a0 * bf2f((unsigned short)(q.x & 0xFFFF)) + a1 * bf2f((unsigned short)(q.x >> 16))
                 + a2 * bf2f((unsigned short)(q.y & 0xFFFF)) + a3 * bf2f((unsigned short)(q.y >> 16));
        float v1 = a0 * bf2f((unsigned short)(q.z & 0xFFFF)) + a1 * bf2f((unsigned short)(q.z >> 16))
                 + a2 * bf2f((unsigned short)(q.w & 0xFFFF)) + a3 * bf2f((unsigned short)(q.w >> 16));
        if (v) unsafeAtomicAdd(&out_acc2[(size_t)cl * 16 + c2], __floats2half2_rn(v0, v1));
    }
}

// K6: out = fp16 out_acc2 + bias
__global__ void k_final(const __half2* __restrict__ out_acc2, const float4* __restrict__ bias,
                        float4* __restrict__ out, int N)
{
    int i = blockIdx.x * 256 + threadIdx.x;
    if (i >= N * 8) return;
    float4 b = bias[i & 7];
    float2 f0 = __half22float2(out_acc2[i * 2]);
    float2 f1 = __half22float2(out_acc2[i * 2 + 1]);
    out[i] = make_float4(f0.x + b.x, f0.y + b.y, f1.x + b.z, f1.y + b.w);
}

extern "C" void kernel_launch(void* const* d_in, const int* in_sizes, int n_in,
                              void* d_out, int out_size, void* d_ws, size_t ws_size,
                              hipStream_t stream)
{
    const float* x    = (const float*)d_in[0];
    const int*   ei   = (const int*)d_in[1];
    const float* w    = (const float*)d_in[2];
    const float* att  = (const float*)d_in[3];
    const float* bias = (const float*)d_in[4];
    float* out = (float*)d_out;
    int N = in_sizes[0] / FDIM;
    int E = in_sizes[1] / 2;

    unsigned short* xwh = (unsigned short*)d_ws;              // N*128 bf16  (12.8 MB)
    float* a_src    = (float*)(xwh + (size_t)N * FDIM);       // N*4 f32
    float* a_dst    = a_src + (size_t)N * HEADS;              // N*4 f32
    float* seg      = a_dst + (size_t)N * HEADS;              // N*4 f32   (zeroed)
    __half2* out_acc2 = (__half2*)(seg + (size_t)N * HEADS);  // N*16 half2 (zeroed, contig)
    unsigned short* wt_hi = (unsigned short*)(out_acc2 + (size_t)N * 16); // 128*128 bf16
    unsigned short* wt_lo = wt_hi + FDIM * FDIM;                          // 128*128 bf16
    int* meta = (int*)(wt_lo + FDIM * FDIM);                  // 32 ints
    uint4* recs = (uint4*)(meta + 32);                        // E*16B sorted records

    int nz4 = N * 5;   // (seg N*4 + out_acc2 N*16-as-f32) / 4
    int bpb = (E / NB + E / 32 + 15) / 16;   // 25% headroom over E/8 edges per bucket

    k_wsplit<<<(FDIM * FDIM) / 256, 256, 0, stream>>>(w, wt_hi, wt_lo, meta);
    k_hist<<<512, 256, 0, stream>>>(ei, E, N, meta);
    k_scan8<<<1, 64, 0, stream>>>(meta);
    k_gemm<<<(N + BM - 1) / BM, 256, 0, stream>>>(x, wt_hi, wt_lo, att, xwh, a_src, a_dst,
                                                  (float4*)seg, nz4, N);
    k_esum<<<(E + 255) / 256, 256, 0, stream>>>(ei, E, N, a_src, a_dst, seg, meta, recs);
    k_scatter<<<NB * bpb, 256, 0, stream>>>(recs, meta, seg, xwh, out_acc2, bpb);
    k_final<<<(N * 8 + 255) / 256, 256, 0, stream>>>(out_acc2, (const float4*)bias, (float4*)out, N);
}

// Round 3
// 227.078 us; speedup vs baseline: 1.5490x; 1.5490x over previous
//
#include <hip/hip_runtime.h>
#include <hip/hip_fp16.h>

#define FDIM 128
#define HEADS 4
#define CD 32
#define BM 64
#define NB 8            // XCD buckets
#define CHUNK 1024      // edges per sort block

typedef __attribute__((ext_vector_type(8))) short bfrag;   // 8 bf16 (4 VGPRs)
typedef __attribute__((ext_vector_type(4))) float ffrag;   // 4 f32 accum

static __device__ __forceinline__ unsigned short f2bf(float v) {
    unsigned u = __float_as_uint(v);
    u += 0x7FFF + ((u >> 16) & 1);          // round-nearest-even
    return (unsigned short)(u >> 16);
}
static __device__ __forceinline__ float bf2f(unsigned short u) {
    return __uint_as_float(((unsigned)u) << 16);
}

// K0: split W into bf16 hi/lo, transpose to [n][k].
__global__ __launch_bounds__(256) void k_wsplit(const float* __restrict__ w,
                                                unsigned short* __restrict__ wt_hi,
                                                unsigned short* __restrict__ wt_lo)
{
    int i = blockIdx.x * 256 + threadIdx.x;      // 16384 elements, coalesced read
    float v = w[i];
    unsigned short h = f2bf(v);
    float r = v - bf2f(h);
    int k = i >> 7, n = i & 127;
    wt_hi[n * FDIM + k] = h;
    wt_lo[n * FDIM + k] = f2bf(r);
}

// K0b: per-(chunk,bucket) histogram. cntT transposed: cntT[b][blk].
__global__ __launch_bounds__(256) void k_hist(const int* __restrict__ ei, int E, int N,
                                              int* __restrict__ cntT, int nblk)
{
    __shared__ int h[NB];
    int t = threadIdx.x;
    if (t < NB) h[t] = 0;
    __syncthreads();
    int base = blockIdx.x * CHUNK;
#pragma unroll
    for (int i = 0; i < CHUNK / 256; i++) {
        int e = base + i * 256 + t;
        if (e < E) atomicAdd(&h[(ei[e] * NB) / N], 1);
    }
    __syncthreads();
    if (t < NB) cntT[t * nblk + blockIdx.x] = h[t];
}

// K0c: one block, 8 waves. Wave w: exclusive prefix over cntT[w][*] -> prefT[w][*]
// (bucket-relative), totals -> exclusive bucket bases meta[8..16]. No contended atomics.
__global__ __launch_bounds__(512) void k_scan(const int* __restrict__ cntT,
                                              int* __restrict__ prefT,
                                              int* __restrict__ meta, int nblk)
{
    __shared__ int tot[NB];
    int t = threadIdx.x, w = t >> 6, lane = t & 63;
    int carry = 0;
    for (int c0 = 0; c0 < nblk; c0 += 64) {
        int i = c0 + lane;
        int v = (i < nblk) ? cntT[w * nblk + i] : 0;
        int x = v;
#pragma unroll
        for (int d = 1; d < 64; d <<= 1) { int y = __shfl_up(x, d, 64); if (lane >= d) x += y; }
        if (i < nblk) prefT[w * nblk + i] = carry + x - v;
        carry += __shfl(x, 63, 64);
    }
    if (lane == 0) tot[w] = carry;
    __syncthreads();
    if (t == 0) {
        int s = 0;
        for (int b = 0; b < NB; b++) { meta[8 + b] = s; s += tot[b]; }
        meta[16] = s;
    }
}

// K1: MFMA GEMM (split bf16: hi*hi + hi*lo + lo*hi ~= fp32) + logits. Unchanged.
__global__ __launch_bounds__(256) void k_gemm(const float* __restrict__ x,
                                              const unsigned short* __restrict__ wt_hi,
                                              const unsigned short* __restrict__ wt_lo,
                                              const float* __restrict__ att,
                                              unsigned short* __restrict__ xwh,
                                              float* __restrict__ a_src,
                                              float* __restrict__ a_dst,
                                              float4* __restrict__ zero_base,
                                              int nz4, int N)
{
    __shared__ float accs[BM * 132];     // 64 rows x 128 cols, stride 132 (33.8KB)
    __shared__ float attl[HEADS * 2 * CD];
    int t = threadIdx.x;
    int row0 = blockIdx.x * BM;
    for (int i = blockIdx.x * 256 + t; i < nz4; i += gridDim.x * 256)
        zero_base[i] = make_float4(0.f, 0.f, 0.f, 0.f);
    attl[t] = att[t];

    int l = t & 63, wv = t >> 6;
    int la = l & 15, lr = l >> 4;
    int arow = row0 + wv * 16 + la;
    bool aval = arow < N;
    const float* xbase = x + (size_t)arow * FDIM + lr * 8;

    ffrag acc[8] = {};
#pragma unroll
    for (int ks = 0; ks < 4; ks++) {
        float xv[8] = {0.f, 0.f, 0.f, 0.f, 0.f, 0.f, 0.f, 0.f};
        if (aval) {
            float4 f0 = *(const float4*)(xbase + ks * 32);
            float4 f1 = *(const float4*)(xbase + ks * 32 + 4);
            xv[0] = f0.x; xv[1] = f0.y; xv[2] = f0.z; xv[3] = f0.w;
            xv[4] = f1.x; xv[5] = f1.y; xv[6] = f1.z; xv[7] = f1.w;
        }
        bfrag ah, al;
#pragma unroll
        for (int j = 0; j < 8; j++) {
            unsigned short h = f2bf(xv[j]);
            ah[j] = (short)h;
            al[j] = (short)f2bf(xv[j] - bf2f(h));
        }
        int boff = ks * 32 + lr * 8;
#pragma unroll
        for (int ct = 0; ct < 8; ct++) {
            int o = (ct * 16 + la) * FDIM + boff;
            bfrag bh = *(const bfrag*)(wt_hi + o);
            bfrag bl = *(const bfrag*)(wt_lo + o);
            acc[ct] = __builtin_amdgcn_mfma_f32_16x16x32_bf16(ah, bh, acc[ct], 0, 0, 0);
            acc[ct] = __builtin_amdgcn_mfma_f32_16x16x32_bf16(ah, bl, acc[ct], 0, 0, 0);
            acc[ct] = __builtin_amdgcn_mfma_f32_16x16x32_bf16(al, bh, acc[ct], 0, 0, 0);
        }
    }

#pragma unroll
    for (int i = 0; i < 4; i++) {
        int r = row0 + wv * 16 + lr * 4 + i;
        if (r < N) {
            uint2 pa, pb;
            pa.x = (unsigned)f2bf(acc[0][i]) | ((unsigned)f2bf(acc[2][i]) << 16);
            pa.y = (unsigned)f2bf(acc[4][i]) | ((unsigned)f2bf(acc[6][i]) << 16);
            pb.x = (unsigned)f2bf(acc[1][i]) | ((unsigned)f2bf(acc[3][i]) << 16);
            pb.y = (unsigned)f2bf(acc[5][i]) | ((unsigned)f2bf(acc[7][i]) << 16);
            *(uint2*)&xwh[(size_t)r * FDIM + la * 4] = pa;
            *(uint2*)&xwh[(size_t)r * FDIM + 64 + la * 4] = pb;
        }
    }
#pragma unroll
    for (int ct = 0; ct < 8; ct++)
#pragma unroll
        for (int i = 0; i < 4; i++)
            accs[(wv * 16 + lr * 4 + i) * 132 + ct * 16 + la] = acc[ct][i];
    __syncthreads();
    int row = t >> 2, h = t & 3;
    const float* ap = &attl[h * 2 * CD];
    const float* xr = &accs[row * 132 + h * CD];
    float s = 0.f, d = 0.f;
#pragma unroll 8
    for (int c = 0; c < CD; c++) { float v = xr[c]; s += v * ap[c]; d += v * ap[CD + c]; }
    int n = row0 + row;
    if (n < N) { a_src[n * 4 + h] = s; a_dst[n * 4 + h] = d; }
}

// K4: round-1 form. Lane-per-(edge,head): 4 adjacent lanes share one 16B sector,
// seg atomics coalesce per-instruction. ealpha fp16 coalesced.
__global__ __launch_bounds__(256) void k_esum(const int* __restrict__ ei, int E,
                                              const float* __restrict__ a_src,
                                              const float* __restrict__ a_dst,
                                              float* __restrict__ seg,
                                              __half* __restrict__ ealpha)
{
    int gid = blockIdx.x * 256 + threadIdx.x;
    if (gid >= E * HEADS) return;
    int e = gid >> 2, h = gid & 3;
    int r = ei[e], cl = ei[E + e];
    float a = a_src[r * 4 + h] + a_dst[cl * 4 + h];
    a = a >= 0.f ? a : 0.2f * a;
    float ex = __expf(a);
    ealpha[gid] = __float2half(ex);
    atomicAdd(&seg[r * 4 + h], ex);
}

// K4b: bucketed record emit, deterministic placement (no global atomics).
// rec = (r, cl, half2(ex0,ex1), half2(ex2,ex3)) = 16B.
__global__ __launch_bounds__(256) void k_sortrec(const int* __restrict__ ei, int E, int N,
                                                 const __half* __restrict__ ealpha,
                                                 const int* __restrict__ prefT,
                                                 const int* __restrict__ meta,
                                                 uint4* __restrict__ recs, int nblk)
{
    __shared__ int lcnt[NB];
    __shared__ int boff[NB];
    int t = threadIdx.x, blk = blockIdx.x;
    if (t < NB) { lcnt[t] = 0; boff[t] = meta[8 + t] + prefT[t * nblk + blk]; }
    __syncthreads();
    int base = blk * CHUNK;
#pragma unroll
    for (int i = 0; i < CHUNK / 256; i++) {
        int e = base + i * 256 + t;
        if (e < E) {
            int r = ei[e], cl = ei[E + e];
            uint2 a = *(const uint2*)(ealpha + (size_t)e * 4);
            int b = (r * NB) / N;
            int loc = atomicAdd(&lcnt[b], 1);
            recs[boff[b] + loc] = make_uint4((unsigned)r, (unsigned)cl, a.x, a.y);
        }
    }
}

// K5: bucketed scatter — block bid handles bucket bid%8 (XCD-aligned via round-robin
// dispatch), so the xwh gather working set is 1.6MB -> per-XCD L2-resident.
__global__ __launch_bounds__(256) void k_scatter(const uint4* __restrict__ recs,
                                                 const int* __restrict__ meta,
                                                 const float* __restrict__ seg,
                                                 const unsigned short* __restrict__ xwh,
                                                 __half2* __restrict__ out_acc2, int bpb)
{
    int t = threadIdx.x;
    int le = t >> 4, c2 = t & 15, lane = t & 63;   // 16 edges/block
    int b = blockIdx.x & 7;
    int lo = meta[8 + b], hi = meta[9 + b];
    int cnt = hi - lo;
    for (int chunk = blockIdx.x >> 3; chunk * 16 < cnt; chunk += bpb) {
        int idx = lo + chunk * 16 + le;
        bool v = idx < hi;
        uint4 rec = recs[v ? idx : lo];
        int r = (int)rec.x, cl = (int)rec.y;
        float av = 0.f;
        if (v && c2 < 4) {
            unsigned az = (c2 < 2) ? rec.z : rec.w;       // no runtime reg indexing
            __half2 hh = *(__half2*)&az;
            float a = (c2 & 1) ? __high2float(hh) : __low2float(hh);
            av = 0.25f * a / (seg[r * 4 + c2] + 1e-16f);
        }
        uint4 q = ((const uint4*)(xwh + (size_t)r * FDIM))[c2];
        float a0 = __shfl(av, (lane & 48) + 0, 64);
        float a1 = __shfl(av, (lane & 48) + 1, 64);
        float a2 = __shfl(av, (lane & 48) + 2, 64);
        float a3 = __shfl(av, (lane & 48) + 3, 64);
        float v0 = a0 * bf2f((unsigned short)(q.x & 0xFFFF)) + a1 * bf2f((unsigned short)(q.x >> 16))
                 + a2 * bf2f((unsigned short)(q.y & 0xFFFF)) + a3 * bf2f((unsigned short)(q.y >> 16));
        float v1 = a0 * bf2f((unsigned short)(q.z & 0xFFFF)) + a1 * bf2f((unsigned short)(q.z >> 16))
                 + a2 * bf2f((unsigned short)(q.w & 0xFFFF)) + a3 * bf2f((unsigned short)(q.w >> 16));
        if (v) unsafeAtomicAdd(&out_acc2[(size_t)cl * 16 + c2], __floats2half2_rn(v0, v1));
    }
}

// K6: out = fp16 out_acc2 + bias
__global__ void k_final(const __half2* __restrict__ out_acc2, const float4* __restrict__ bias,
                        float4* __restrict__ out, int N)
{
    int i = blockIdx.x * 256 + threadIdx.x;
    if (i >= N * 8) return;
    float4 b = bias[i & 7];
    float2 f0 = __half22float2(out_acc2[i * 2]);
    float2 f1 = __half22float2(out_acc2[i * 2 + 1]);
    out[i] = make_float4(f0.x + b.x, f0.y + b.y, f1.x + b.z, f1.y + b.w);
}

extern "C" void kernel_launch(void* const* d_in, const int* in_sizes, int n_in,
                              void* d_out, int out_size, void* d_ws, size_t ws_size,
                              hipStream_t stream)
{
    const float* x    = (const float*)d_in[0];
    const int*   ei   = (const int*)d_in[1];
    const float* w    = (const float*)d_in[2];
    const float* att  = (const float*)d_in[3];
    const float* bias = (const float*)d_in[4];
    float* out = (float*)d_out;
    int N = in_sizes[0] / FDIM;
    int E = in_sizes[1] / 2;
    int nblk = (E + CHUNK - 1) / CHUNK;

    unsigned short* xwh = (unsigned short*)d_ws;              // N*128 bf16  (12.8 MB)
    float* a_src    = (float*)(xwh + (size_t)N * FDIM);       // N*4 f32
    float* a_dst    = a_src + (size_t)N * HEADS;              // N*4 f32
    float* seg      = a_dst + (size_t)N * HEADS;              // N*4 f32   (zeroed)
    __half2* out_acc2 = (__half2*)(seg + (size_t)N * HEADS);  // N*16 half2 (zeroed, contig)
    uint4* recs     = (uint4*)(out_acc2 + (size_t)N * 16);    // E*16B sorted records
    __half* ealpha  = (__half*)(recs + (size_t)E);            // E*4 fp16
    unsigned short* wt_hi = (unsigned short*)(ealpha + (size_t)E * HEADS); // 128*128 bf16
    unsigned short* wt_lo = wt_hi + FDIM * FDIM;              // 128*128 bf16
    int* meta = (int*)(wt_lo + FDIM * FDIM);                  // 32 ints
    int* cntT = meta + 32;                                    // NB*nblk
    int* prefT = cntT + NB * nblk;                            // NB*nblk

    int nz4 = N * 5;   // (seg N*4 + out_acc2 N*16-as-f32) / 4
    int bpb = (E / NB + E / 32 + 15) / 16;   // 25% headroom over E/8 edges per bucket

    k_wsplit<<<(FDIM * FDIM) / 256, 256, 0, stream>>>(w, wt_hi, wt_lo);
    k_hist<<<nblk, 256, 0, stream>>>(ei, E, N, cntT, nblk);
    k_scan<<<1, 512, 0, stream>>>(cntT, prefT, meta, nblk);
    k_gemm<<<(N + BM - 1) / BM, 256, 0, stream>>>(x, wt_hi, wt_lo, att, xwh, a_src, a_dst,
                                                  (float4*)seg, nz4, N);
    k_esum<<<(E * HEADS + 255) / 256, 256, 0, stream>>>(ei, E, a_src, a_dst, seg, ealpha);
    k_sortrec<<<nblk, 256, 0, stream>>>(ei, E, N, ealpha, prefT, meta, recs, nblk);
    k_scatter<<<NB * bpb, 256, 0, stream>>>(recs, meta, seg, xwh, out_acc2, bpb);
    k_final<<<(N * 8 + 255) / 256, 256, 0, stream>>>(out_acc2, (const float4*)bias, (float4*)out, N);
}